// Round 1
// baseline (512.725 us; speedup 1.0000x reference)
//
#include <hip/hip_runtime.h>
#include <hip/hip_bf16.h>
#include <math.h>

// ---------------------------------------------------------------------------
// GATGNN global attention:  softmax_seg( MLP([x|glbl]) )  on MI355X (gfx950)
// Strategy: bf16 MFMA for the two 512-wide GEMMs, fp32 everywhere else.
// ---------------------------------------------------------------------------

#define NSEG 1024

typedef __attribute__((ext_vector_type(8))) short short8;
typedef __attribute__((ext_vector_type(4))) float f32x4;

__device__ __forceinline__ float bf2f(unsigned short u) {
  union { unsigned int i; float f; } c; c.i = ((unsigned int)u) << 16; return c.f;
}
__device__ __forceinline__ unsigned short f2bf(float f) {
  __hip_bfloat16 h = __float2bfloat16(f);
  return *reinterpret_cast<unsigned short*>(&h);
}

__device__ __forceinline__ void gll16(const unsigned short* g, unsigned short* l) {
  __builtin_amdgcn_global_load_lds(
      (const __attribute__((address_space(1))) void*)g,
      (__attribute__((address_space(3))) void*)l, 16, 0, 0);
}

// ---------------------------------------------------------------------------
// Pack A0 = [x | glbl | zeros] as bf16 [Mp, 640]; pad rows (>=N) zeroed.
// One thread per 8-element chunk (16B store).
// ---------------------------------------------------------------------------
__global__ __launch_bounds__(256) void pack_a0(const float* __restrict__ x,
                                               const float* __restrict__ gx,
                                               unsigned short* __restrict__ A0,
                                               int N, int Mp) {
  int t = blockIdx.x * 256 + threadIdx.x;
  if (t >= Mp * 80) return;
  int row = t / 80, c = t % 80;
  union { unsigned short u[8]; uint4 q; } v;
  if (row >= N) {
#pragma unroll
    for (int j = 0; j < 8; ++j) v.u[j] = 0;
  } else if (c < 64) {
    const float4* p = (const float4*)(x + (size_t)row * 512 + c * 8);
    float4 a = p[0], b = p[1];
    v.u[0] = f2bf(a.x); v.u[1] = f2bf(a.y); v.u[2] = f2bf(a.z); v.u[3] = f2bf(a.w);
    v.u[4] = f2bf(b.x); v.u[5] = f2bf(b.y); v.u[6] = f2bf(b.z); v.u[7] = f2bf(b.w);
  } else {
#pragma unroll
    for (int j = 0; j < 8; ++j) {
      int col = c * 8 + j;
      float f = (col < 620) ? gx[(size_t)row * 108 + (col - 512)] : 0.f;
      v.u[j] = f2bf(f);
    }
  }
  *reinterpret_cast<uint4*>(A0 + (size_t)row * 640 + c * 8) = v.q;
}

// W0 [620,512] f32 -> W0T bf16 [512,640] (transposed, K padded with zeros)
__global__ __launch_bounds__(256) void pack_w0t(const float* __restrict__ W0,
                                                unsigned short* __restrict__ W0T) {
  int t = blockIdx.x * 256 + threadIdx.x;
  if (t >= 512 * 640) return;
  int n = t / 640, k = t % 640;
  float f = (k < 620) ? W0[(size_t)k * 512 + n] : 0.f;
  W0T[t] = f2bf(f);
}

// W1 [512,512] f32 -> W1T bf16 [512,512] (transposed)
__global__ __launch_bounds__(256) void pack_w1t(const float* __restrict__ W1,
                                                unsigned short* __restrict__ W1T) {
  int t = blockIdx.x * 256 + threadIdx.x;
  if (t >= 512 * 512) return;
  int n = t / 512, k = t % 512;
  W1T[t] = f2bf(W1[(size_t)k * 512 + n]);
}

// ---------------------------------------------------------------------------
// GEMM: C[M,512] = act(A[M,K] * BT[512,K]^T + bias).  128x128 tile, BK=32,
// 4 waves (2x2), 64x64 per wave, mfma_f32_16x16x32_bf16, global_load_lds
// staging, single barrier per K-step, bf16 output with fused softplus.
// A rows padded to multiple of 128 (pad rows produce garbage, never read).
// ---------------------------------------------------------------------------
template <int K, bool ACT>
__global__ __launch_bounds__(256) void gemm_bf16(const unsigned short* __restrict__ A,
                                                 const unsigned short* __restrict__ BT,
                                                 const float* __restrict__ bias,
                                                 unsigned short* __restrict__ C) {
  constexpr int KT = K / 32;
  __shared__ unsigned short As[2][128 * 32];
  __shared__ unsigned short Bs[2][128 * 32];
  const int tid = threadIdx.x;
  const int nt = blockIdx.x & 3;   // 512/128 = 4 col tiles
  const int mt = blockIdx.x >> 2;
  const int lane = tid & 63;
  const int wid = tid >> 6;
  const int wm = wid >> 1, wn = wid & 1;   // 2x2 wave grid
  const int lrow = lane & 15;
  const int lk = (lane >> 4) << 3;         // k-offset 0/8/16/24

  const unsigned short* Ag = A + (size_t)mt * 128 * K;
  const unsigned short* Bg = BT + (size_t)nt * 128 * K;

  f32x4 acc[4][4] = {};

  // prologue: stage k-tile 0 into buffer 0 (8KB each of A,B; 2 insts/thread ea.)
#pragma unroll
  for (int i = 0; i < 2; ++i) {
    int f = i * 256 + tid;
    int row = f >> 2, kp = (f & 3) << 3;
    gll16(Ag + row * K + kp, &As[0][f * 8]);
    gll16(Bg + row * K + kp, &Bs[0][f * 8]);
  }

  for (int kt = 0; kt < KT; ++kt) {
    const int cur = kt & 1;
    __syncthreads();  // staging of buf[cur] complete (vmcnt drained), reads of buf[cur^1] done
    if (kt + 1 < KT) {
      const int kb = (kt + 1) * 32;
#pragma unroll
      for (int i = 0; i < 2; ++i) {
        int f = i * 256 + tid;
        int row = f >> 2, kp = (f & 3) << 3;
        gll16(Ag + row * K + kb + kp, &As[cur ^ 1][f * 8]);
        gll16(Bg + row * K + kb + kp, &Bs[cur ^ 1][f * 8]);
      }
    }
    short8 af[4], bf[4];
#pragma unroll
    for (int mi = 0; mi < 4; ++mi)
      af[mi] = *reinterpret_cast<const short8*>(&As[cur][(wm * 64 + mi * 16 + lrow) * 32 + lk]);
#pragma unroll
    for (int ni = 0; ni < 4; ++ni)
      bf[ni] = *reinterpret_cast<const short8*>(&Bs[cur][(wn * 64 + ni * 16 + lrow) * 32 + lk]);
#pragma unroll
    for (int mi = 0; mi < 4; ++mi)
#pragma unroll
      for (int ni = 0; ni < 4; ++ni)
        acc[mi][ni] = __builtin_amdgcn_mfma_f32_16x16x32_bf16(af[mi], bf[ni], acc[mi][ni], 0, 0, 0);
  }

  // epilogue: bias + (optional) softplus, bf16 store
  // D layout (m89): col = lane&15, row = (lane>>4)*4 + reg
#pragma unroll
  for (int ni = 0; ni < 4; ++ni) {
    const int col = nt * 128 + wn * 64 + ni * 16 + lrow;
    const float bb = bias[col];
#pragma unroll
    for (int mi = 0; mi < 4; ++mi) {
      const int row0 = mt * 128 + wm * 64 + mi * 16 + ((lane >> 4) << 2);
      f32x4 v = acc[mi][ni];
#pragma unroll
      for (int r = 0; r < 4; ++r) {
        float z = v[r] + bb;
        if (ACT) z = fmaxf(z, 0.f) + log1pf(expf(-fabsf(z)));  // softplus = logaddexp(z,0)
        C[(size_t)(row0 + r) * 512 + col] = f2bf(z);
      }
    }
  }
}

// ---------------------------------------------------------------------------
// logits[n] = sum_k H1[n,k] * W2[k] + b2 ; one wave per row (lane covers 8 k's)
// ---------------------------------------------------------------------------
__global__ __launch_bounds__(256) void logits_k(const unsigned short* __restrict__ H1,
                                                const float* __restrict__ W2,
                                                const float* __restrict__ b2,
                                                float* __restrict__ logits, int N) {
  const int lane = threadIdx.x & 63;
  const int row = blockIdx.x * 4 + (threadIdx.x >> 6);
  if (row >= N) return;
  uint4 u = *reinterpret_cast<const uint4*>(H1 + (size_t)row * 512 + lane * 8);
  const unsigned int* uw = reinterpret_cast<const unsigned int*>(&u);
  float s = 0.f;
#pragma unroll
  for (int j = 0; j < 4; ++j) {
    unsigned int w = uw[j];
    s += bf2f((unsigned short)(w & 0xffffu)) * W2[lane * 8 + 2 * j];
    s += bf2f((unsigned short)(w >> 16)) * W2[lane * 8 + 2 * j + 1];
  }
#pragma unroll
  for (int o = 32; o; o >>= 1) s += __shfl_down(s, o);
  if (lane == 0) logits[row] = s + b2[0];
}

// ---------------------------------------------------------------------------
// Per-segment softmax: one block per segment; batch is sorted -> binary search
// ---------------------------------------------------------------------------
__global__ __launch_bounds__(256) void segsoftmax(const float* __restrict__ logits,
                                                  const int* __restrict__ batch,
                                                  float* __restrict__ out, int N) {
  const int g = blockIdx.x;
  const int tid = threadIdx.x;
  int lo = 0, hi = N;
  while (lo < hi) { int mid = (lo + hi) >> 1; if (batch[mid] < g) lo = mid + 1; else hi = mid; }
  const int beg = lo;
  hi = N;
  while (lo < hi) { int mid = (lo + hi) >> 1; if (batch[mid] < g + 1) lo = mid + 1; else hi = mid; }
  const int end = lo;
  if (beg >= end) return;

  __shared__ float sh[4];
  float m = -INFINITY;
  for (int i = beg + tid; i < end; i += 256) m = fmaxf(m, logits[i]);
#pragma unroll
  for (int o = 32; o; o >>= 1) m = fmaxf(m, __shfl_down(m, o));
  if ((tid & 63) == 0) sh[tid >> 6] = m;
  __syncthreads();
  m = fmaxf(fmaxf(sh[0], sh[1]), fmaxf(sh[2], sh[3]));
  __syncthreads();

  float s = 0.f;
  for (int i = beg + tid; i < end; i += 256) s += expf(logits[i] - m);
#pragma unroll
  for (int o = 32; o; o >>= 1) s += __shfl_down(s, o);
  if ((tid & 63) == 0) sh[tid >> 6] = s;
  __syncthreads();
  s = sh[0] + sh[1] + sh[2] + sh[3];

  const float inv = 1.f / (s + 1e-16f);
  for (int i = beg + tid; i < end; i += 256) out[i] = expf(logits[i] - m) * inv;
}

// ---------------------------------------------------------------------------
extern "C" void kernel_launch(void* const* d_in, const int* in_sizes, int n_in,
                              void* d_out, int out_size, void* d_ws, size_t ws_size,
                              hipStream_t stream) {
  const float* x = (const float*)d_in[0];
  const int* batch = (const int*)d_in[1];
  const float* gx = (const float*)d_in[2];
  const float* W0 = (const float*)d_in[3];
  const float* b0 = (const float*)d_in[4];
  const float* W1 = (const float*)d_in[5];
  const float* b1 = (const float*)d_in[6];
  const float* W2 = (const float*)d_in[7];
  const float* b2 = (const float*)d_in[8];
  float* out = (float*)d_out;

  const int N = in_sizes[1];                 // 100000
  const int Mp = ((N + 127) / 128) * 128;    // 100096
  const int Mtiles = Mp / 128;

  auto align256 = [](size_t v) { return (v + 255) & ~(size_t)255; };
  char* ws = (char*)d_ws;
  size_t off = 0;
  unsigned short* A0 = (unsigned short*)(ws + off);  off = align256(off + (size_t)Mp * 640 * 2);
  unsigned short* W0T = (unsigned short*)(ws + off); off = align256(off + (size_t)512 * 640 * 2);
  unsigned short* W1T = (unsigned short*)(ws + off); off = align256(off + (size_t)512 * 512 * 2);
  unsigned short* H0 = (unsigned short*)(ws + off);  off = align256(off + (size_t)Mp * 512 * 2);
  unsigned short* H1 = (unsigned short*)(ws + off);  off = align256(off + (size_t)Mp * 512 * 2);
  float* logits = (float*)(ws + off);                off = align256(off + (size_t)Mp * 4);
  (void)ws_size; (void)n_in; (void)out_size;

  pack_w0t<<<(512 * 640 + 255) / 256, 256, 0, stream>>>(W0, W0T);
  pack_w1t<<<(512 * 512 + 255) / 256, 256, 0, stream>>>(W1, W1T);
  pack_a0<<<(Mp * 80 + 255) / 256, 256, 0, stream>>>(x, gx, A0, N, Mp);

  gemm_bf16<640, true><<<Mtiles * 4, 256, 0, stream>>>(A0, W0T, b0, H0);
  gemm_bf16<512, true><<<Mtiles * 4, 256, 0, stream>>>(H0, W1T, b1, H1);

  logits_k<<<(N + 3) / 4, 256, 0, stream>>>(H1, W2, b2, logits, N);
  segsoftmax<<<NSEG, 256, 0, stream>>>(logits, batch, out, N);
}

// Round 2
// 352.828 us; speedup vs baseline: 1.4532x; 1.4532x over previous
//
#include <hip/hip_runtime.h>
#include <hip/hip_bf16.h>
#include <math.h>

// ---------------------------------------------------------------------------
// GATGNN global attention:  softmax_seg( MLP([x|glbl]) )  on MI355X (gfx950)
// R1: cheap softplus, 128x256 tile (64x128/wave), operand-swapped MFMA for
//     vector stores, LDS chunk-swizzle, GEMM1+logits fusion (H1 never stored).
// ---------------------------------------------------------------------------

#define NSEG 1024

typedef __attribute__((ext_vector_type(8))) short short8;
typedef __attribute__((ext_vector_type(4))) float f32x4;

__device__ __forceinline__ float bf2f(unsigned short u) {
  union { unsigned int i; float f; } c; c.i = ((unsigned int)u) << 16; return c.f;
}
__device__ __forceinline__ unsigned short f2bf(float f) {
  __hip_bfloat16 h = __float2bfloat16(f);
  return *reinterpret_cast<unsigned short*>(&h);
}
__device__ __forceinline__ float softplus_fast(float z) {
  // softplus(z) = max(z,0) + log(1+exp(-|z|)); hw exp/log, bf16-accurate
  float t = __expf(-fabsf(z));
  return fmaxf(z, 0.f) + __logf(1.f + t);
}

__device__ __forceinline__ void gll16(const unsigned short* g, unsigned short* l) {
  __builtin_amdgcn_global_load_lds(
      (const __attribute__((address_space(1))) void*)g,
      (__attribute__((address_space(3))) void*)l, 16, 0, 0);
}

// ---------------------------------------------------------------------------
// Pack A0 = [x | glbl | zeros] as bf16 [Mp, 640]; pad rows (>=N) zeroed.
// ---------------------------------------------------------------------------
__global__ __launch_bounds__(256) void pack_a0(const float* __restrict__ x,
                                               const float* __restrict__ gx,
                                               unsigned short* __restrict__ A0,
                                               int N, int Mp) {
  int t = blockIdx.x * 256 + threadIdx.x;
  if (t >= Mp * 80) return;
  int row = t / 80, c = t % 80;
  union { unsigned short u[8]; uint4 q; } v;
  if (row >= N) {
#pragma unroll
    for (int j = 0; j < 8; ++j) v.u[j] = 0;
  } else if (c < 64) {
    const float4* p = (const float4*)(x + (size_t)row * 512 + c * 8);
    float4 a = p[0], b = p[1];
    v.u[0] = f2bf(a.x); v.u[1] = f2bf(a.y); v.u[2] = f2bf(a.z); v.u[3] = f2bf(a.w);
    v.u[4] = f2bf(b.x); v.u[5] = f2bf(b.y); v.u[6] = f2bf(b.z); v.u[7] = f2bf(b.w);
  } else {
#pragma unroll
    for (int j = 0; j < 8; ++j) {
      int col = c * 8 + j;
      float f = (col < 620) ? gx[(size_t)row * 108 + (col - 512)] : 0.f;
      v.u[j] = f2bf(f);
    }
  }
  *reinterpret_cast<uint4*>(A0 + (size_t)row * 640 + c * 8) = v.q;
}

// W0 [620,512] f32 -> W0T bf16 [512,640] (transposed, K padded with zeros)
__global__ __launch_bounds__(256) void pack_w0t(const float* __restrict__ W0,
                                                unsigned short* __restrict__ W0T) {
  int t = blockIdx.x * 256 + threadIdx.x;
  if (t >= 512 * 640) return;
  int n = t / 640, k = t % 640;
  float f = (k < 620) ? W0[(size_t)k * 512 + n] : 0.f;
  W0T[t] = f2bf(f);
}

// W1 [512,512] f32 -> W1T bf16 [512,512] (transposed)
__global__ __launch_bounds__(256) void pack_w1t(const float* __restrict__ W1,
                                                unsigned short* __restrict__ W1T) {
  int t = blockIdx.x * 256 + threadIdx.x;
  if (t >= 512 * 512) return;
  int n = t / 512, k = t % 512;
  W1T[t] = f2bf(W1[(size_t)k * 512 + n]);
}

__global__ __launch_bounds__(256) void zero_f32(float* __restrict__ p, int n) {
  int i = blockIdx.x * 256 + threadIdx.x;
  if (i < n) p[i] = 0.f;
}

// ---------------------------------------------------------------------------
// GEMM: Z[M,512] = A[M,K] * BT[512,K]^T + bias; 128x256 block tile, BK=32,
// 4 waves (2x2), 64x128 per wave, mfma(bf,af) so each thread holds 4
// consecutive output COLUMNS (vector store / W2-dot).
//  FUSE=false: C = bf16(softplus(Z))                (layer 0 -> H0)
//  FUSE=true : logits[m] += sum_n softplus(Z[m,n])*W2[n]   (layer 1+2 fused)
// LDS chunk-swizzle: slot s of row r holds global chunk s ^ ((r>>1)&3).
// ---------------------------------------------------------------------------
template <int K, bool FUSE>
__global__ __launch_bounds__(256, 2) void gemm_bf16(const unsigned short* __restrict__ A,
                                                    const unsigned short* __restrict__ BT,
                                                    const float* __restrict__ bias,
                                                    unsigned short* __restrict__ C,
                                                    const float* __restrict__ W2,
                                                    float* __restrict__ logits) {
  constexpr int KT = K / 32;
  __shared__ unsigned short As[2][128 * 32];
  __shared__ unsigned short Bs[2][256 * 32];
  const int tid = threadIdx.x;
  const int nt = blockIdx.x & 1;   // 512/256 = 2 col tiles
  const int mt = blockIdx.x >> 1;
  const int lane = tid & 63;
  const int wid = tid >> 6;
  const int wm = wid >> 1, wn = wid & 1;   // 2x2 wave grid: 64 rows x 128 cols each
  const int lm = lane & 15;
  const int rch = lane >> 4;               // k-chunk 0..3 (8 elems each)

  const unsigned short* Ag = A + (size_t)mt * 128 * K;
  const unsigned short* Bg = BT + (size_t)nt * 256 * K;

  f32x4 acc[4][8] = {};

  auto stage = [&](int buf, int kb) {
#pragma unroll
    for (int i = 0; i < 2; ++i) {
      int f = i * 256 + tid;
      int row = f >> 2;
      int sc = ((f & 3) ^ ((row >> 1) & 3)) << 3;
      gll16(Ag + (size_t)row * K + kb + sc, &As[buf][f * 8]);
    }
#pragma unroll
    for (int i = 0; i < 4; ++i) {
      int f = i * 256 + tid;
      int row = f >> 2;
      int sc = ((f & 3) ^ ((row >> 1) & 3)) << 3;
      gll16(Bg + (size_t)row * K + kb + sc, &Bs[buf][f * 8]);
    }
  };

  stage(0, 0);

  for (int kt = 0; kt < KT; ++kt) {
    const int cur = kt & 1;
    __syncthreads();  // drains vmcnt: buf[cur] staged; buf[cur^1] reads done
    if (kt + 1 < KT) stage(cur ^ 1, (kt + 1) * 32);

    short8 af[4], bfr[8];
#pragma unroll
    for (int mi = 0; mi < 4; ++mi) {
      int row = wm * 64 + mi * 16 + lm;
      af[mi] = *reinterpret_cast<const short8*>(
          &As[cur][row * 32 + ((rch ^ ((row >> 1) & 3)) << 3)]);
    }
#pragma unroll
    for (int ni = 0; ni < 8; ++ni) {
      int row = wn * 128 + ni * 16 + lm;
      bfr[ni] = *reinterpret_cast<const short8*>(
          &Bs[cur][row * 32 + ((rch ^ ((row >> 1) & 3)) << 3)]);
    }
#pragma unroll
    for (int mi = 0; mi < 4; ++mi)
#pragma unroll
      for (int ni = 0; ni < 8; ++ni)
        acc[mi][ni] = __builtin_amdgcn_mfma_f32_16x16x32_bf16(bfr[ni], af[mi], acc[mi][ni], 0, 0, 0);
  }

  // Transposed D layout: thread holds C[m][n0..n0+3]
  //   m  = mt*128 + wm*64 + mi*16 + (lane&15)
  //   n0 = nt*256 + wn*128 + ni*16 + (lane>>4)*4
#pragma unroll
  for (int mi = 0; mi < 4; ++mi) {
    const int m = mt * 128 + wm * 64 + mi * 16 + lm;
    float part = 0.f;
#pragma unroll
    for (int ni = 0; ni < 8; ++ni) {
      const int n0 = nt * 256 + wn * 128 + ni * 16 + (rch << 2);
      const f32x4 bb = *reinterpret_cast<const f32x4*>(bias + n0);
      f32x4 v = acc[mi][ni];
      if constexpr (!FUSE) {
        union { unsigned short u[4]; uint2 q; } o;
#pragma unroll
        for (int r = 0; r < 4; ++r) o.u[r] = f2bf(softplus_fast(v[r] + bb[r]));
        *reinterpret_cast<uint2*>(C + (size_t)m * 512 + n0) = o.q;
      } else {
        const f32x4 wv = *reinterpret_cast<const f32x4*>(W2 + n0);
#pragma unroll
        for (int r = 0; r < 4; ++r) part += softplus_fast(v[r] + bb[r]) * wv[r];
      }
    }
    if constexpr (FUSE) {
      part += __shfl_xor(part, 16);
      part += __shfl_xor(part, 32);
      if (lane < 16) atomicAdd(logits + m, part);
    }
  }
}

// ---------------------------------------------------------------------------
// Per-segment softmax: one block per segment; batch is sorted -> binary search
// (b2 is omitted everywhere: softmax is shift-invariant.)
// ---------------------------------------------------------------------------
__global__ __launch_bounds__(256) void segsoftmax(const float* __restrict__ logits,
                                                  const int* __restrict__ batch,
                                                  float* __restrict__ out, int N) {
  const int g = blockIdx.x;
  const int tid = threadIdx.x;
  int lo = 0, hi = N;
  while (lo < hi) { int mid = (lo + hi) >> 1; if (batch[mid] < g) lo = mid + 1; else hi = mid; }
  const int beg = lo;
  hi = N;
  while (lo < hi) { int mid = (lo + hi) >> 1; if (batch[mid] < g + 1) lo = mid + 1; else hi = mid; }
  const int end = lo;
  if (beg >= end) return;

  __shared__ float sh[4];
  float m = -INFINITY;
  for (int i = beg + tid; i < end; i += 256) m = fmaxf(m, logits[i]);
#pragma unroll
  for (int o = 32; o; o >>= 1) m = fmaxf(m, __shfl_down(m, o));
  if ((tid & 63) == 0) sh[tid >> 6] = m;
  __syncthreads();
  m = fmaxf(fmaxf(sh[0], sh[1]), fmaxf(sh[2], sh[3]));
  __syncthreads();

  float s = 0.f;
  for (int i = beg + tid; i < end; i += 256) s += expf(logits[i] - m);
#pragma unroll
  for (int o = 32; o; o >>= 1) s += __shfl_down(s, o);
  if ((tid & 63) == 0) sh[tid >> 6] = s;
  __syncthreads();
  s = sh[0] + sh[1] + sh[2] + sh[3];

  const float inv = 1.f / (s + 1e-16f);
  for (int i = beg + tid; i < end; i += 256) out[i] = expf(logits[i] - m) * inv;
}

// ---------------------------------------------------------------------------
extern "C" void kernel_launch(void* const* d_in, const int* in_sizes, int n_in,
                              void* d_out, int out_size, void* d_ws, size_t ws_size,
                              hipStream_t stream) {
  const float* x = (const float*)d_in[0];
  const int* batch = (const int*)d_in[1];
  const float* gx = (const float*)d_in[2];
  const float* W0 = (const float*)d_in[3];
  const float* b0 = (const float*)d_in[4];
  const float* W1 = (const float*)d_in[5];
  const float* b1 = (const float*)d_in[6];
  const float* W2 = (const float*)d_in[7];
  float* out = (float*)d_out;

  const int N = in_sizes[1];                 // 100000
  const int Mp = ((N + 127) / 128) * 128;    // 100096
  const int Mtiles = Mp / 128;

  auto align256 = [](size_t v) { return (v + 255) & ~(size_t)255; };
  char* ws = (char*)d_ws;
  size_t off = 0;
  unsigned short* A0 = (unsigned short*)(ws + off);  off = align256(off + (size_t)Mp * 640 * 2);
  unsigned short* W0T = (unsigned short*)(ws + off); off = align256(off + (size_t)512 * 640 * 2);
  unsigned short* W1T = (unsigned short*)(ws + off); off = align256(off + (size_t)512 * 512 * 2);
  unsigned short* H0 = (unsigned short*)(ws + off);  off = align256(off + (size_t)Mp * 512 * 2);
  float* logits = (float*)(ws + off);                off = align256(off + (size_t)Mp * 4);
  (void)ws_size; (void)n_in; (void)out_size;

  pack_w0t<<<(512 * 640 + 255) / 256, 256, 0, stream>>>(W0, W0T);
  pack_w1t<<<(512 * 512 + 255) / 256, 256, 0, stream>>>(W1, W1T);
  pack_a0<<<(Mp * 80 + 255) / 256, 256, 0, stream>>>(x, gx, A0, N, Mp);
  zero_f32<<<(Mp + 255) / 256, 256, 0, stream>>>(logits, Mp);

  gemm_bf16<640, false><<<Mtiles * 2, 256, 0, stream>>>(A0, W0T, b0, H0, nullptr, nullptr);
  gemm_bf16<512, true><<<Mtiles * 2, 256, 0, stream>>>(H0, W1T, b1, nullptr, W2, logits);

  segsoftmax<<<NSEG, 256, 0, stream>>>(logits, batch, out, N);
}